// Round 4
// baseline (134.412 us; speedup 1.0000x reference)
//
#include <hip/hip_runtime.h>

#define LOG2E 1.44269504088896340736f

typedef _Float16 half8 __attribute__((ext_vector_type(8)));
typedef float f32x16 __attribute__((ext_vector_type(16)));
typedef unsigned int uv4 __attribute__((ext_vector_type(4)));

__device__ __forceinline__ unsigned pk16(float a, float b) {
  return __builtin_bit_cast(unsigned, __builtin_amdgcn_cvt_pkrtz(a, b));
}

// v_permlane32_swap_b32: a.hi(lanes32-63) <-> b.lo(lanes0-31)
__device__ __forceinline__ void plswap(unsigned &a, unsigned &b) {
  asm volatile("v_permlane32_swap_b32 %0, %1" : "+v"(a), "+v"(b));
}

__device__ __forceinline__ f32x16 mfma16(half8 a, half8 b, f32x16 c) {
  return __builtin_amdgcn_mfma_f32_32x32x16_f16(a, b, c, 0, 0, 0);
}

// Build the B-operand fragment (k = 8h+j within a 16-k block) from 8 C-layout
// register values p0..p7 (rows crow(r,h) = (r&3)+8*(r>>2)+4h).  m214 recipe.
__device__ __forceinline__ half8 pack_frag(float p0, float p1, float p2, float p3,
                                           float p4, float p5, float p6, float p7) {
  unsigned a0 = pk16(p0, p1), a1 = pk16(p2, p3);
  unsigned b0 = pk16(p4, p5), b1 = pk16(p6, p7);
  plswap(a0, b0);
  plswap(a1, b1);
  uv4 u; u.x = a0; u.y = a1; u.z = b0; u.w = b1;
  return __builtin_bit_cast(half8, u);
}

// ---------------------------------------------------------------------------
// prep: Q = x@W1^T, K = x@W2^T (fp32 accum -> f16), VT[b][d][n] = f16(x)
// block: 256 threads, one 64-row n-tile of one batch. grid = 4*128 = 512.
// ---------------------------------------------------------------------------
__global__ __launch_bounds__(256) void prep_kernel(
    const float* __restrict__ x, const float* __restrict__ W1,
    const float* __restrict__ W2, _Float16* __restrict__ Qg,
    _Float16* __restrict__ Kg, _Float16* __restrict__ VTg) {
  __shared__ float xs[64][68];
  __shared__ float w1s[64][68];
  __shared__ float w2s[64][68];
  const int tid = threadIdx.x;
  const int b = blockIdx.x >> 7;
  const int n0 = (blockIdx.x & 127) << 6;
  const float* xp = x + (size_t)(b * 8192 + n0) * 64;
  for (int i = tid; i < 4096; i += 256) {
    int r = i >> 6, c = i & 63;
    xs[r][c] = xp[i];
    w1s[r][c] = W1[i];
    w2s[r][c] = W2[i];
  }
  __syncthreads();

  const int e = tid & 63, r0 = tid >> 6;
  float qa[16], ka[16];
#pragma unroll
  for (int r = 0; r < 16; ++r) { qa[r] = 0.f; ka[r] = 0.f; }
#pragma unroll 1
  for (int dc = 0; dc < 4; ++dc) {
    float4 w1c[4], w2c[4];
#pragma unroll
    for (int i = 0; i < 4; ++i) {
      w1c[i] = *(const float4*)&w1s[e][dc * 16 + i * 4];
      w2c[i] = *(const float4*)&w2s[e][dc * 16 + i * 4];
    }
#pragma unroll
    for (int rr = 0; rr < 16; ++rr) {
      const int r = (rr << 2) | r0;
#pragma unroll
      for (int i = 0; i < 4; ++i) {
        float4 xv = *(const float4*)&xs[r][dc * 16 + i * 4];
        qa[rr] = fmaf(xv.x, w1c[i].x, qa[rr]);
        qa[rr] = fmaf(xv.y, w1c[i].y, qa[rr]);
        qa[rr] = fmaf(xv.z, w1c[i].z, qa[rr]);
        qa[rr] = fmaf(xv.w, w1c[i].w, qa[rr]);
        ka[rr] = fmaf(xv.x, w2c[i].x, ka[rr]);
        ka[rr] = fmaf(xv.y, w2c[i].y, ka[rr]);
        ka[rr] = fmaf(xv.z, w2c[i].z, ka[rr]);
        ka[rr] = fmaf(xv.w, w2c[i].w, ka[rr]);
      }
    }
  }
#pragma unroll
  for (int rr = 0; rr < 16; ++rr) {
    const int r = (rr << 2) | r0;
    size_t o = (size_t)(b * 8192 + n0 + r) * 64 + e;
    Qg[o] = (_Float16)qa[rr];
    Kg[o] = (_Float16)ka[rr];
  }
  // VT: transpose x tile, f16. thread -> d = tid/4, 16-n chunk = (tid&3)*16
  const int d = tid >> 2, nc = (tid & 3) << 4;
  half8 v0, v1;
#pragma unroll
  for (int i = 0; i < 8; ++i) {
    v0[i] = (_Float16)xs[nc + i][d];
    v1[i] = (_Float16)xs[nc + 8 + i][d];
  }
  _Float16* vp = VTg + (size_t)(b * 64 + d) * 8192 + n0 + nc;
  *(half8*)vp = v0;
  *(half8*)(vp + 8) = v1;
}

// ---------------------------------------------------------------------------
// attn: flash attention, swapped QK^T (ST = mfma(K,Q)), fused GCN epilogue.
// block: 256 thr = 4 waves, each wave owns 32 q rows (QBLK=128).
// KV-split S in {1,2,4}: grid = S*4*64 blocks; block handles ntiles=128/S
// kv tiles. S==1 -> relu store to out. S>1 -> per-split normalized Z (f32)
// + running max Ma / denom La; merge_kernel recombines.
// lsum via ones-MFMA (idle matrix pipe) replaces the VALU sum tree.
// defer-max (T13, THR=8) skips the O-rescale on most tiles.
// launch_bounds(256,3): ~145 live VGPRs; (256,4) forced a 64-VGPR cap and
// AGPR spill-shuttle traffic that doubled VALU busy (round-3 post-mortem).
// ---------------------------------------------------------------------------
#define GL(src, dst)                                                           \
  __builtin_amdgcn_global_load_lds(                                            \
      (const __attribute__((address_space(1))) unsigned*)(src),                \
      (__attribute__((address_space(3))) unsigned*)(dst), 16, 0, 0)

#define STAGE(buf, t)                                                          \
  {                                                                            \
    GL(srcK0 + ((size_t)(t) << 13), &sK[buf][w << 10]);                        \
    GL(srcK0 + ((size_t)(t) << 13) + 1024, &sK[buf][(w << 10) + 512]);         \
    GL(srcV0 + ((size_t)(t) << 7), &sV[buf][w << 10]);                         \
    GL(srcV0 + ((size_t)(t) << 7) + 131072, &sV[buf][(w << 10) + 512]);        \
  }

__global__ __launch_bounds__(256, 3) void attn_kernel(
    const _Float16* __restrict__ Qg, const _Float16* __restrict__ Kg,
    const _Float16* __restrict__ VTg, const float* __restrict__ Gw,
    float* __restrict__ out, float* __restrict__ Zp,
    float* __restrict__ Ma, float* __restrict__ La, int ntiles, int S) {
  __shared__ _Float16 sK[2][4096];
  __shared__ _Float16 sV[2][4096];
  const int tid = threadIdx.x;
  const int w = tid >> 6;   // 0..3
  const int l = tid & 63;
  const int h = l >> 5;
  const int r31 = l & 31;
  const int bid = blockIdx.x;
  const int qblk = bid & 63;
  const int b = (bid >> 6) & 3;
  const int s = bid >> 8;
  const int t0 = s * ntiles;
  const int qrow = (qblk << 7) + (w << 5) + r31;

  // Q fragments: B-operand layout (col=q=l&31, k = kb*16 + 8h + j)
  half8 qf[4];
  {
    const _Float16* qp = Qg + ((size_t)(b * 8192 + qrow) << 6) + (h << 3);
#pragma unroll
    for (int kb = 0; kb < 4; ++kb) qf[kb] = *(const half8*)(qp + (kb << 4));
  }
  half8 ones;
#pragma unroll
  for (int j = 0; j < 8; ++j) ones[j] = (_Float16)1.f;

  f32x16 o0 = (f32x16)0.f, o1 = (f32x16)0.f, ls = (f32x16)0.f;
  float m = -INFINITY, mc = 0.f;

  const int srow = (w << 4) | (l >> 3);  // first staged row (wave covers 16)
  const int sblk = (l & 7) ^ (l >> 3);   // swizzled 16B block in source
  const char* srcK0 =
      (const char*)(Kg + ((size_t)(b * 8192 + t0 * 64 + srow) << 6)) + (sblk << 4);
  const char* srcV0 =
      (const char*)(VTg + ((size_t)(b * 64 + srow) << 13) + t0 * 64) + (sblk << 4);

  STAGE(0, 0);
  __syncthreads();

#pragma unroll 1
  for (int t = 0; t < ntiles; ++t) {
    const int cur = t & 1;
    if (t + 1 < ntiles) STAGE(cur ^ 1, t + 1);

    const char* pK = (const char*)sK[cur];
    const char* pV = (const char*)sV[cur];

    // ---- ST = K . Q^T : lane has q = l&31, kv = crow(r,h) (+32 for st1)
    f32x16 st0 = (f32x16)0.f, st1 = (f32x16)0.f;
    __builtin_amdgcn_s_setprio(1);
#pragma unroll
    for (int kb = 0; kb < 4; ++kb) {
      const int sl = ((((kb << 1) | h)) ^ (l & 7)) << 4;
      half8 k0 = *(const half8*)(pK + (r31 << 7) + sl);
      half8 k1 = *(const half8*)(pK + ((32 + r31) << 7) + sl);
      st0 = mfma16(k0, qf[kb], st0);
      st1 = mfma16(k1, qf[kb], st1);
    }
    __builtin_amdgcn_s_setprio(0);

    // ---- online softmax; max via max3-friendly tree, defer-max rescale
    float mx[8];
#pragma unroll
    for (int r = 0; r < 8; ++r)
      mx[r] = fmaxf(fmaxf(st0[r], st0[r + 8]), fmaxf(st1[r], st1[r + 8]));
    float pm = fmaxf(fmaxf(fmaxf(fmaxf(mx[0], mx[1]), mx[2]),
                           fmaxf(fmaxf(mx[3], mx[4]), mx[5])),
                     fmaxf(mx[6], mx[7]));
    pm = fmaxf(pm, __shfl_xor(pm, 32));
    if (__any(pm > m + 8.f)) {  // defer-max (T13)
      float mn = fmaxf(m, pm);
      float sc = __builtin_amdgcn_exp2f((m - mn) * LOG2E);
#pragma unroll
      for (int r = 0; r < 16; ++r) { o0[r] *= sc; o1[r] *= sc; ls[r] *= sc; }
      m = mn;
      mc = mn * LOG2E;
    }
#pragma unroll
    for (int r = 0; r < 16; ++r) {
      st0[r] = __builtin_amdgcn_exp2f(fmaf(st0[r], LOG2E, -mc));
      st1[r] = __builtin_amdgcn_exp2f(fmaf(st1[r], LOG2E, -mc));
    }

    // ---- P -> f16 B-fragments (cvt_pk + permlane32_swap)
    half8 pf[4];
    pf[0] = pack_frag(st0[0], st0[1], st0[2], st0[3], st0[4], st0[5], st0[6], st0[7]);
    pf[1] = pack_frag(st0[8], st0[9], st0[10], st0[11], st0[12], st0[13], st0[14], st0[15]);
    pf[2] = pack_frag(st1[0], st1[1], st1[2], st1[3], st1[4], st1[5], st1[6], st1[7]);
    pf[3] = pack_frag(st1[8], st1[9], st1[10], st1[11], st1[12], st1[13], st1[14], st1[15]);

    // ---- O^T += V^T . P^T ; lsum via ones-MFMA on the same pipe
    __builtin_amdgcn_s_setprio(1);
#pragma unroll
    for (int kb = 0; kb < 4; ++kb) {
      const int sl = ((((kb << 1) | h)) ^ (l & 7)) << 4;
      half8 v0 = *(const half8*)(pV + (r31 << 7) + sl);
      half8 v1 = *(const half8*)(pV + ((32 + r31) << 7) + sl);
      o0 = mfma16(v0, pf[kb], o0);
      o1 = mfma16(v1, pf[kb], o1);
      ls = mfma16(ones, pf[kb], ls);
    }
    __builtin_amdgcn_s_setprio(0);
    __syncthreads();
  }

  // ---- epilogue: normalize, fused GCN: Z^T = G^T . O^T  (f16 mfma)
  const float lsum = ls[0];
  const float inv = 1.f / lsum;
#pragma unroll
  for (int r = 0; r < 16; ++r) { o0[r] *= inv; o1[r] *= inv; }

  half8 ga[2][4];
#pragma unroll
  for (int eb = 0; eb < 2; ++eb) {
#pragma unroll
    for (int kb = 0; kb < 4; ++kb) {
      half8 tt;
#pragma unroll
      for (int j = 0; j < 8; ++j) {
        int dd = (kb << 4) + (h << 3) + j;
        tt[j] = (_Float16)Gw[(dd << 6) + (eb << 5) + r31];
      }
      ga[eb][kb] = tt;
    }
  }
  half8 of[4];
  of[0] = pack_frag(o0[0], o0[1], o0[2], o0[3], o0[4], o0[5], o0[6], o0[7]);
  of[1] = pack_frag(o0[8], o0[9], o0[10], o0[11], o0[12], o0[13], o0[14], o0[15]);
  of[2] = pack_frag(o1[0], o1[1], o1[2], o1[3], o1[4], o1[5], o1[6], o1[7]);
  of[3] = pack_frag(o1[8], o1[9], o1[10], o1[11], o1[12], o1[13], o1[14], o1[15]);
  f32x16 z0 = (f32x16)0.f, z1 = (f32x16)0.f;
#pragma unroll
  for (int kb = 0; kb < 4; ++kb) {
    z0 = mfma16(ga[0][kb], of[kb], z0);
    z1 = mfma16(ga[1][kb], of[kb], z1);
  }
  if (S == 1) {
    float* Orow = out + (size_t)(b * 8192 + qrow) * 64;
#pragma unroll
    for (int r = 0; r < 16; ++r) {
      const int e0 = (r & 3) + ((r >> 2) << 3) + (h << 2);
      Orow[e0] = fmaxf(z0[r], 0.f);
      Orow[e0 + 32] = fmaxf(z1[r], 0.f);
    }
  } else {
    float* Zrow = Zp + ((size_t)((s << 2) + b) * 8192 + qrow) * 64;
#pragma unroll
    for (int r = 0; r < 16; ++r) {
      const int e0 = (r & 3) + ((r >> 2) << 3) + (h << 2);
      Zrow[e0] = z0[r];
      Zrow[e0 + 32] = z1[r];
    }
    if (h == 0) {
      size_t si = (size_t)((s << 2) + b) * 8192 + qrow;
      Ma[si] = m;
      La[si] = lsum;
    }
  }
}

// ---------------------------------------------------------------------------
// merge: combine S splits + relu. grid 2048*256 threads, one float4 each.
// ---------------------------------------------------------------------------
__global__ __launch_bounds__(256) void merge_kernel(
    const float* __restrict__ Zp, const float* __restrict__ Ma,
    const float* __restrict__ La, float* __restrict__ out, int S) {
  const int idx = blockIdx.x * 256 + threadIdx.x;  // quad index
  const int R = idx >> 4;
  const int c4 = (idx & 15) << 2;
  float M = -INFINITY;
  for (int s = 0; s < S; ++s) M = fmaxf(M, Ma[R + s * 32768]);
  float a[4];
  float asum = 0.f;
  for (int s = 0; s < S; ++s) {
    a[s] = __builtin_amdgcn_exp2f((Ma[R + s * 32768] - M) * LOG2E) *
           La[R + s * 32768];
    asum += a[s];
  }
  const float inv = 1.f / asum;
  float4 acc = make_float4(0.f, 0.f, 0.f, 0.f);
  for (int s = 0; s < S; ++s) {
    const float4 z = *(const float4*)(Zp + ((size_t)(R + s * 32768) * 64 + c4));
    const float as = a[s];
    acc.x = fmaf(as, z.x, acc.x);
    acc.y = fmaf(as, z.y, acc.y);
    acc.z = fmaf(as, z.z, acc.z);
    acc.w = fmaf(as, z.w, acc.w);
  }
  float4 y;
  y.x = fmaxf(acc.x * inv, 0.f);
  y.y = fmaxf(acc.y * inv, 0.f);
  y.z = fmaxf(acc.z * inv, 0.f);
  y.w = fmaxf(acc.w * inv, 0.f);
  *(float4*)(out + (size_t)R * 64 + c4) = y;
}

extern "C" void kernel_launch(void* const* d_in, const int* in_sizes, int n_in,
                              void* d_out, int out_size, void* d_ws, size_t ws_size,
                              hipStream_t stream) {
  const float* x = (const float*)d_in[0];
  const float* W1 = (const float*)d_in[1];
  const float* W2 = (const float*)d_in[2];
  const float* G = (const float*)d_in[3];
  char* ws = (char*)d_ws;
  const size_t MB = (size_t)1 << 20;
  _Float16* Qg = (_Float16*)(ws);
  _Float16* Kg = (_Float16*)(ws + 4 * MB);
  _Float16* VTg = (_Float16*)(ws + 8 * MB);
  float* out = (float*)d_out;

  // KV-split factor gated on workspace size:
  //   S=4 needs 12MB(QKV) + 32MB(Zp f32) + 1MB(Ma/La) = 45MB
  //   S=2 needs 12 + 16 + 0.5 = 28.5MB
  int S;
  if (ws_size >= 46 * MB) S = 4;
  else if (ws_size >= 29 * MB) S = 2;
  else S = 1;

  float* Zp = (float*)(ws + 12 * MB);
  float* Ma = (float*)(ws + 12 * MB + (size_t)S * 8 * MB);
  float* La = Ma + (size_t)S * 32768;

  prep_kernel<<<dim3(512), dim3(256), 0, stream>>>(x, W1, W2, Qg, Kg, VTg);
  attn_kernel<<<dim3(S * 256), dim3(256), 0, stream>>>(Qg, Kg, VTg, G, out, Zp,
                                                       Ma, La, 128 / S, S);
  if (S > 1)
    merge_kernel<<<dim3(2048), dim3(256), 0, stream>>>(Zp, Ma, La, out, S);
}

// Round 5
// 123.201 us; speedup vs baseline: 1.0910x; 1.0910x over previous
//
#include <hip/hip_runtime.h>

#define LOG2E 1.44269504088896340736f

typedef _Float16 half8 __attribute__((ext_vector_type(8)));
typedef _Float16 half4v __attribute__((ext_vector_type(4)));
typedef float f32x16 __attribute__((ext_vector_type(16)));
typedef unsigned int uv4 __attribute__((ext_vector_type(4)));

__device__ __forceinline__ unsigned pk16(float a, float b) {
  return __builtin_bit_cast(unsigned, __builtin_amdgcn_cvt_pkrtz(a, b));
}

// v_permlane32_swap_b32: a.hi(lanes32-63) <-> b.lo(lanes0-31)
__device__ __forceinline__ void plswap(unsigned &a, unsigned &b) {
  asm volatile("v_permlane32_swap_b32 %0, %1" : "+v"(a), "+v"(b));
}

__device__ __forceinline__ f32x16 mfma16(half8 a, half8 b, f32x16 c) {
  return __builtin_amdgcn_mfma_f32_32x32x16_f16(a, b, c, 0, 0, 0);
}

// Build the B-operand fragment (k = 8h+j within a 16-k block) from 8 C-layout
// register values p0..p7 (rows crow(r,h) = (r&3)+8*(r>>2)+4h).  m214 recipe.
__device__ __forceinline__ half8 pack_frag(float p0, float p1, float p2, float p3,
                                           float p4, float p5, float p6, float p7) {
  unsigned a0 = pk16(p0, p1), a1 = pk16(p2, p3);
  unsigned b0 = pk16(p4, p5), b1 = pk16(p6, p7);
  plswap(a0, b0);
  plswap(a1, b1);
  uv4 u; u.x = a0; u.y = a1; u.z = b0; u.w = b1;
  return __builtin_bit_cast(half8, u);
}

// ---------------------------------------------------------------------------
// prep: Q = x@W1^T, K = x@W2^T (fp32 accum -> f16), VT[b][d][n] = f16(x)
// block: 256 threads, one 64-row n-tile of one batch. grid = 4*128 = 512.
// ---------------------------------------------------------------------------
__global__ __launch_bounds__(256) void prep_kernel(
    const float* __restrict__ x, const float* __restrict__ W1,
    const float* __restrict__ W2, _Float16* __restrict__ Qg,
    _Float16* __restrict__ Kg, _Float16* __restrict__ VTg) {
  __shared__ float xs[64][68];
  __shared__ float w1s[64][68];
  __shared__ float w2s[64][68];
  const int tid = threadIdx.x;
  const int b = blockIdx.x >> 7;
  const int n0 = (blockIdx.x & 127) << 6;
  const float* xp = x + (size_t)(b * 8192 + n0) * 64;
  for (int i = tid; i < 4096; i += 256) {
    int r = i >> 6, c = i & 63;
    xs[r][c] = xp[i];
    w1s[r][c] = W1[i];
    w2s[r][c] = W2[i];
  }
  __syncthreads();

  const int e = tid & 63, r0 = tid >> 6;
  float qa[16], ka[16];
#pragma unroll
  for (int r = 0; r < 16; ++r) { qa[r] = 0.f; ka[r] = 0.f; }
#pragma unroll 1
  for (int dc = 0; dc < 4; ++dc) {
    float4 w1c[4], w2c[4];
#pragma unroll
    for (int i = 0; i < 4; ++i) {
      w1c[i] = *(const float4*)&w1s[e][dc * 16 + i * 4];
      w2c[i] = *(const float4*)&w2s[e][dc * 16 + i * 4];
    }
#pragma unroll
    for (int rr = 0; rr < 16; ++rr) {
      const int r = (rr << 2) | r0;
#pragma unroll
      for (int i = 0; i < 4; ++i) {
        float4 xv = *(const float4*)&xs[r][dc * 16 + i * 4];
        qa[rr] = fmaf(xv.x, w1c[i].x, qa[rr]);
        qa[rr] = fmaf(xv.y, w1c[i].y, qa[rr]);
        qa[rr] = fmaf(xv.z, w1c[i].z, qa[rr]);
        qa[rr] = fmaf(xv.w, w1c[i].w, qa[rr]);
        ka[rr] = fmaf(xv.x, w2c[i].x, ka[rr]);
        ka[rr] = fmaf(xv.y, w2c[i].y, ka[rr]);
        ka[rr] = fmaf(xv.z, w2c[i].z, ka[rr]);
        ka[rr] = fmaf(xv.w, w2c[i].w, ka[rr]);
      }
    }
  }
#pragma unroll
  for (int rr = 0; rr < 16; ++rr) {
    const int r = (rr << 2) | r0;
    size_t o = (size_t)(b * 8192 + n0 + r) * 64 + e;
    Qg[o] = (_Float16)qa[rr];
    Kg[o] = (_Float16)ka[rr];
  }
  // VT: transpose x tile, f16. thread -> d = tid/4, 16-n chunk = (tid&3)*16
  const int d = tid >> 2, nc = (tid & 3) << 4;
  half8 v0, v1;
#pragma unroll
  for (int i = 0; i < 8; ++i) {
    v0[i] = (_Float16)xs[nc + i][d];
    v1[i] = (_Float16)xs[nc + 8 + i][d];
  }
  _Float16* vp = VTg + (size_t)(b * 64 + d) * 8192 + n0 + nc;
  *(half8*)vp = v0;
  *(half8*)(vp + 8) = v1;
}

// ---------------------------------------------------------------------------
// attn: flash attention, swapped QK^T (ST = mfma(K,Q)), fused GCN epilogue.
// block: 256 thr = 4 waves, each wave owns 32 q rows (QBLK=128).
// KV-split S in {1,2,4}: grid = S*4*64 blocks (XCD-chunk-swizzled); block
// handles ntiles=128/S kv tiles. S==1 -> relu store to out. S>1 -> per-split
// normalized Z (f16) + running max Ma / denom La; merge_kernel recombines.
// lsum via VALU tree (frees 16 AGPRs vs ones-MFMA -> more resident waves;
// round-4 post-mortem: combined VGPR+AGPR footprint caps occupancy).
// defer-max (T13, THR=8) skips the O-rescale on most tiles.
// launch_bounds(256,4): round-3 measured best (64 VGPR, 33% occ).
// ---------------------------------------------------------------------------
#define GL(src, dst)                                                           \
  __builtin_amdgcn_global_load_lds(                                            \
      (const __attribute__((address_space(1))) unsigned*)(src),                \
      (__attribute__((address_space(3))) unsigned*)(dst), 16, 0, 0)

#define STAGE(buf, t)                                                          \
  {                                                                            \
    GL(srcK0 + ((size_t)(t) << 13), &sK[buf][w << 10]);                        \
    GL(srcK0 + ((size_t)(t) << 13) + 1024, &sK[buf][(w << 10) + 512]);         \
    GL(srcV0 + ((size_t)(t) << 7), &sV[buf][w << 10]);                         \
    GL(srcV0 + ((size_t)(t) << 7) + 131072, &sV[buf][(w << 10) + 512]);        \
  }

__global__ __launch_bounds__(256, 4) void attn_kernel(
    const _Float16* __restrict__ Qg, const _Float16* __restrict__ Kg,
    const _Float16* __restrict__ VTg, const float* __restrict__ Gw,
    float* __restrict__ out, _Float16* __restrict__ Zp,
    float* __restrict__ Ma, float* __restrict__ La, int ntiles, int S) {
  __shared__ _Float16 sK[2][4096];
  __shared__ _Float16 sV[2][4096];
  const int tid = threadIdx.x;
  const int w = tid >> 6;   // 0..3
  const int l = tid & 63;
  const int h = l >> 5;
  const int r31 = l & 31;
  // XCD-chunked bid swizzle (T1): blocks sharing one (s,b) K/V stream land on
  // one XCD -> stream is L2-resident. nwg = S*256, always divisible by 8.
  const int nwg = gridDim.x;
  const int hw = blockIdx.x;
  const int bid = (hw & 7) * (nwg >> 3) + (hw >> 3);
  const int qblk = bid & 63;
  const int b = (bid >> 6) & 3;
  const int s = bid >> 8;
  const int t0 = s * ntiles;
  const int qrow = (qblk << 7) + (w << 5) + r31;

  // Q fragments: B-operand layout (col=q=l&31, k = kb*16 + 8h + j)
  half8 qf[4];
  {
    const _Float16* qp = Qg + ((size_t)(b * 8192 + qrow) << 6) + (h << 3);
#pragma unroll
    for (int kb = 0; kb < 4; ++kb) qf[kb] = *(const half8*)(qp + (kb << 4));
  }

  f32x16 o0 = (f32x16)0.f, o1 = (f32x16)0.f;
  float m = -INFINITY, mc = 0.f, lsum = 0.f;

  const int srow = (w << 4) | (l >> 3);  // first staged row (wave covers 16)
  const int sblk = (l & 7) ^ (l >> 3);   // swizzled 16B block in source
  const char* srcK0 =
      (const char*)(Kg + ((size_t)(b * 8192 + t0 * 64 + srow) << 6)) + (sblk << 4);
  const char* srcV0 =
      (const char*)(VTg + ((size_t)(b * 64 + srow) << 13) + t0 * 64) + (sblk << 4);

  STAGE(0, 0);
  __syncthreads();

#pragma unroll 1
  for (int t = 0; t < ntiles; ++t) {
    const int cur = t & 1;
    if (t + 1 < ntiles) STAGE(cur ^ 1, t + 1);

    const char* pK = (const char*)sK[cur];
    const char* pV = (const char*)sV[cur];

    // ---- ST = K . Q^T : lane has q = l&31, kv = crow(r,h) (+32 for st1)
    f32x16 st0 = (f32x16)0.f, st1 = (f32x16)0.f;
    __builtin_amdgcn_s_setprio(1);
#pragma unroll
    for (int kb = 0; kb < 4; ++kb) {
      const int sl = ((((kb << 1) | h)) ^ (l & 7)) << 4;
      half8 k0 = *(const half8*)(pK + (r31 << 7) + sl);
      half8 k1 = *(const half8*)(pK + ((32 + r31) << 7) + sl);
      st0 = mfma16(k0, qf[kb], st0);
      st1 = mfma16(k1, qf[kb], st1);
    }
    __builtin_amdgcn_s_setprio(0);

    // ---- online softmax; max via max3-friendly tree, defer-max rescale
    float mx[8];
#pragma unroll
    for (int r = 0; r < 8; ++r)
      mx[r] = fmaxf(fmaxf(st0[r], st0[r + 8]), fmaxf(st1[r], st1[r + 8]));
    float pm = fmaxf(fmaxf(fmaxf(fmaxf(mx[0], mx[1]), mx[2]),
                           fmaxf(fmaxf(mx[3], mx[4]), mx[5])),
                     fmaxf(mx[6], mx[7]));
    pm = fmaxf(pm, __shfl_xor(pm, 32));
    if (__any(pm > m + 8.f)) {  // defer-max (T13)
      float mn = fmaxf(m, pm);
      float sc = __builtin_amdgcn_exp2f((m - mn) * LOG2E);
#pragma unroll
      for (int r = 0; r < 16; ++r) { o0[r] *= sc; o1[r] *= sc; }
      lsum *= sc;
      m = mn;
      mc = mn * LOG2E;
    }
#pragma unroll
    for (int r = 0; r < 16; ++r) {
      st0[r] = __builtin_amdgcn_exp2f(fmaf(st0[r], LOG2E, -mc));
      st1[r] = __builtin_amdgcn_exp2f(fmaf(st1[r], LOG2E, -mc));
    }

    // ---- lsum: VALU pairwise + tree (costs ~31 VALU; VALU pipe has slack)
    float sm[16];
#pragma unroll
    for (int r = 0; r < 16; ++r) sm[r] = st0[r] + st1[r];
#pragma unroll
    for (int off = 8; off > 0; off >>= 1) {
#pragma unroll
      for (int r = 0; r < 8; ++r)
        if (r < off) sm[r] += sm[r + off];
    }
    lsum += sm[0] + __shfl_xor(sm[0], 32);

    // ---- P -> f16 B-fragments (cvt_pk + permlane32_swap)
    half8 pf[4];
    pf[0] = pack_frag(st0[0], st0[1], st0[2], st0[3], st0[4], st0[5], st0[6], st0[7]);
    pf[1] = pack_frag(st0[8], st0[9], st0[10], st0[11], st0[12], st0[13], st0[14], st0[15]);
    pf[2] = pack_frag(st1[0], st1[1], st1[2], st1[3], st1[4], st1[5], st1[6], st1[7]);
    pf[3] = pack_frag(st1[8], st1[9], st1[10], st1[11], st1[12], st1[13], st1[14], st1[15]);

    // ---- O^T += V^T . P^T
    __builtin_amdgcn_s_setprio(1);
#pragma unroll
    for (int kb = 0; kb < 4; ++kb) {
      const int sl = ((((kb << 1) | h)) ^ (l & 7)) << 4;
      half8 v0 = *(const half8*)(pV + (r31 << 7) + sl);
      half8 v1 = *(const half8*)(pV + ((32 + r31) << 7) + sl);
      o0 = mfma16(v0, pf[kb], o0);
      o1 = mfma16(v1, pf[kb], o1);
    }
    __builtin_amdgcn_s_setprio(0);
    __syncthreads();
  }

  // ---- epilogue: normalize, fused GCN: Z^T = G^T . O^T  (f16 mfma)
  const float inv = 1.f / lsum;
#pragma unroll
  for (int r = 0; r < 16; ++r) { o0[r] *= inv; o1[r] *= inv; }

  half8 ga[2][4];
#pragma unroll
  for (int eb = 0; eb < 2; ++eb) {
#pragma unroll
    for (int kb = 0; kb < 4; ++kb) {
      half8 tt;
#pragma unroll
      for (int j = 0; j < 8; ++j) {
        int dd = (kb << 4) + (h << 3) + j;
        tt[j] = (_Float16)Gw[(dd << 6) + (eb << 5) + r31];
      }
      ga[eb][kb] = tt;
    }
  }
  half8 of[4];
  of[0] = pack_frag(o0[0], o0[1], o0[2], o0[3], o0[4], o0[5], o0[6], o0[7]);
  of[1] = pack_frag(o0[8], o0[9], o0[10], o0[11], o0[12], o0[13], o0[14], o0[15]);
  of[2] = pack_frag(o1[0], o1[1], o1[2], o1[3], o1[4], o1[5], o1[6], o1[7]);
  of[3] = pack_frag(o1[8], o1[9], o1[10], o1[11], o1[12], o1[13], o1[14], o1[15]);
  f32x16 z0 = (f32x16)0.f, z1 = (f32x16)0.f;
#pragma unroll
  for (int kb = 0; kb < 4; ++kb) {
    z0 = mfma16(ga[0][kb], of[kb], z0);
    z1 = mfma16(ga[1][kb], of[kb], z1);
  }
  if (S == 1) {
    float* Orow = out + (size_t)(b * 8192 + qrow) * 64;
#pragma unroll
    for (int r = 0; r < 16; ++r) {
      const int e0 = (r & 3) + ((r >> 2) << 3) + (h << 2);
      Orow[e0] = fmaxf(z0[r], 0.f);
      Orow[e0 + 32] = fmaxf(z1[r], 0.f);
    }
  } else {
    _Float16* Zrow = Zp + ((size_t)((s << 2) + b) * 8192 + qrow) * 64;
#pragma unroll
    for (int r = 0; r < 16; ++r) {
      const int e0 = (r & 3) + ((r >> 2) << 3) + (h << 2);
      Zrow[e0] = (_Float16)z0[r];
      Zrow[e0 + 32] = (_Float16)z1[r];
    }
    if (h == 0) {
      size_t si = (size_t)((s << 2) + b) * 8192 + qrow;
      Ma[si] = m;
      La[si] = lsum;
    }
  }
}

// ---------------------------------------------------------------------------
// merge: combine S splits + relu. grid 2048*256 threads, one 4-elem quad each.
// S is a template param -> a[] fully unrolled, no scratch (rule #20).
// ---------------------------------------------------------------------------
template <int S>
__global__ __launch_bounds__(256) void merge_kernel(
    const _Float16* __restrict__ Zp, const float* __restrict__ Ma,
    const float* __restrict__ La, float* __restrict__ out) {
  const int idx = blockIdx.x * 256 + threadIdx.x;  // quad index
  const int R = idx >> 4;
  const int c4 = (idx & 15) << 2;
  float M = -INFINITY;
#pragma unroll
  for (int s = 0; s < S; ++s) M = fmaxf(M, Ma[R + s * 32768]);
  float a[S];
  float asum = 0.f;
#pragma unroll
  for (int s = 0; s < S; ++s) {
    a[s] = __builtin_amdgcn_exp2f((Ma[R + s * 32768] - M) * LOG2E) *
           La[R + s * 32768];
    asum += a[s];
  }
  const float inv = 1.f / asum;
  float4 acc = make_float4(0.f, 0.f, 0.f, 0.f);
#pragma unroll
  for (int s = 0; s < S; ++s) {
    const half4v z = *(const half4v*)(Zp + ((size_t)(R + s * 32768) * 64 + c4));
    const float as = a[s];
    acc.x = fmaf(as, (float)z[0], acc.x);
    acc.y = fmaf(as, (float)z[1], acc.y);
    acc.z = fmaf(as, (float)z[2], acc.z);
    acc.w = fmaf(as, (float)z[3], acc.w);
  }
  float4 y;
  y.x = fmaxf(acc.x * inv, 0.f);
  y.y = fmaxf(acc.y * inv, 0.f);
  y.z = fmaxf(acc.z * inv, 0.f);
  y.w = fmaxf(acc.w * inv, 0.f);
  *(float4*)(out + (size_t)R * 64 + c4) = y;
}

extern "C" void kernel_launch(void* const* d_in, const int* in_sizes, int n_in,
                              void* d_out, int out_size, void* d_ws, size_t ws_size,
                              hipStream_t stream) {
  const float* x = (const float*)d_in[0];
  const float* W1 = (const float*)d_in[1];
  const float* W2 = (const float*)d_in[2];
  const float* G = (const float*)d_in[3];
  char* ws = (char*)d_ws;
  const size_t MB = (size_t)1 << 20;
  _Float16* Qg = (_Float16*)(ws);
  _Float16* Kg = (_Float16*)(ws + 4 * MB);
  _Float16* VTg = (_Float16*)(ws + 8 * MB);
  float* out = (float*)d_out;

  // KV-split factor gated on workspace size (Zp now f16):
  //   S=4 needs 12MB(QKV) + 16MB(Zp) + 1MB(Ma/La) = 29MB
  //   S=2 needs 12 + 8 + 0.5 = 20.5MB
  int S;
  if (ws_size >= 30 * MB) S = 4;
  else if (ws_size >= 21 * MB) S = 2;
  else S = 1;

  _Float16* Zp = (_Float16*)(ws + 12 * MB);
  float* Ma = (float*)(ws + 12 * MB + (size_t)S * 4 * MB);
  float* La = Ma + (size_t)S * 32768;

  prep_kernel<<<dim3(512), dim3(256), 0, stream>>>(x, W1, W2, Qg, Kg, VTg);
  attn_kernel<<<dim3(S * 256), dim3(256), 0, stream>>>(Qg, Kg, VTg, G, out, Zp,
                                                       Ma, La, 128 / S, S);
  if (S == 4)
    merge_kernel<4><<<dim3(2048), dim3(256), 0, stream>>>(Zp, Ma, La, out);
  else if (S == 2)
    merge_kernel<2><<<dim3(2048), dim3(256), 0, stream>>>(Zp, Ma, La, out);
}

// Round 6
// 122.371 us; speedup vs baseline: 1.0984x; 1.0068x over previous
//
#include <hip/hip_runtime.h>

#define LOG2E 1.44269504088896340736f

typedef _Float16 half8 __attribute__((ext_vector_type(8)));
typedef _Float16 half4v __attribute__((ext_vector_type(4)));
typedef float f32x16 __attribute__((ext_vector_type(16)));
typedef unsigned int uv4 __attribute__((ext_vector_type(4)));

__device__ __forceinline__ unsigned pk16(float a, float b) {
  return __builtin_bit_cast(unsigned, __builtin_amdgcn_cvt_pkrtz(a, b));
}

// v_permlane32_swap_b32: a.hi(lanes32-63) <-> b.lo(lanes0-31)
__device__ __forceinline__ void plswap(unsigned &a, unsigned &b) {
  asm volatile("v_permlane32_swap_b32 %0, %1" : "+v"(a), "+v"(b));
}

__device__ __forceinline__ f32x16 mfma16(half8 a, half8 b, f32x16 c) {
  return __builtin_amdgcn_mfma_f32_32x32x16_f16(a, b, c, 0, 0, 0);
}

// Build the B-operand fragment (k = 8h+j within a 16-k block) from 8 C-layout
// register values p0..p7 (rows crow(r,h) = (r&3)+8*(r>>2)+4h).  m214 recipe.
__device__ __forceinline__ half8 pack_frag(float p0, float p1, float p2, float p3,
                                           float p4, float p5, float p6, float p7) {
  unsigned a0 = pk16(p0, p1), a1 = pk16(p2, p3);
  unsigned b0 = pk16(p4, p5), b1 = pk16(p6, p7);
  plswap(a0, b0);
  plswap(a1, b1);
  uv4 u; u.x = a0; u.y = a1; u.z = b0; u.w = b1;
  return __builtin_bit_cast(half8, u);
}

// ---------------------------------------------------------------------------
// prep: Q = x@W1^T, K = x@W2^T (fp32 accum -> f16), VT[b][d][n] = f16(x)
// block: 256 threads, one 64-row n-tile of one batch. grid = 4*128 = 512.
// ---------------------------------------------------------------------------
__global__ __launch_bounds__(256) void prep_kernel(
    const float* __restrict__ x, const float* __restrict__ W1,
    const float* __restrict__ W2, _Float16* __restrict__ Qg,
    _Float16* __restrict__ Kg, _Float16* __restrict__ VTg) {
  __shared__ float xs[64][68];
  __shared__ float w1s[64][68];
  __shared__ float w2s[64][68];
  const int tid = threadIdx.x;
  const int b = blockIdx.x >> 7;
  const int n0 = (blockIdx.x & 127) << 6;
  const float* xp = x + (size_t)(b * 8192 + n0) * 64;
  for (int i = tid; i < 4096; i += 256) {
    int r = i >> 6, c = i & 63;
    xs[r][c] = xp[i];
    w1s[r][c] = W1[i];
    w2s[r][c] = W2[i];
  }
  __syncthreads();

  const int e = tid & 63, r0 = tid >> 6;
  float qa[16], ka[16];
#pragma unroll
  for (int r = 0; r < 16; ++r) { qa[r] = 0.f; ka[r] = 0.f; }
#pragma unroll 1
  for (int dc = 0; dc < 4; ++dc) {
    float4 w1c[4], w2c[4];
#pragma unroll
    for (int i = 0; i < 4; ++i) {
      w1c[i] = *(const float4*)&w1s[e][dc * 16 + i * 4];
      w2c[i] = *(const float4*)&w2s[e][dc * 16 + i * 4];
    }
#pragma unroll
    for (int rr = 0; rr < 16; ++rr) {
      const int r = (rr << 2) | r0;
#pragma unroll
      for (int i = 0; i < 4; ++i) {
        float4 xv = *(const float4*)&xs[r][dc * 16 + i * 4];
        qa[rr] = fmaf(xv.x, w1c[i].x, qa[rr]);
        qa[rr] = fmaf(xv.y, w1c[i].y, qa[rr]);
        qa[rr] = fmaf(xv.z, w1c[i].z, qa[rr]);
        qa[rr] = fmaf(xv.w, w1c[i].w, qa[rr]);
        ka[rr] = fmaf(xv.x, w2c[i].x, ka[rr]);
        ka[rr] = fmaf(xv.y, w2c[i].y, ka[rr]);
        ka[rr] = fmaf(xv.z, w2c[i].z, ka[rr]);
        ka[rr] = fmaf(xv.w, w2c[i].w, ka[rr]);
      }
    }
  }
#pragma unroll
  for (int rr = 0; rr < 16; ++rr) {
    const int r = (rr << 2) | r0;
    size_t o = (size_t)(b * 8192 + n0 + r) * 64 + e;
    Qg[o] = (_Float16)qa[rr];
    Kg[o] = (_Float16)ka[rr];
  }
  // VT: transpose x tile, f16. thread -> d = tid/4, 16-n chunk = (tid&3)*16
  const int d = tid >> 2, nc = (tid & 3) << 4;
  half8 v0, v1;
#pragma unroll
  for (int i = 0; i < 8; ++i) {
    v0[i] = (_Float16)xs[nc + i][d];
    v1[i] = (_Float16)xs[nc + 8 + i][d];
  }
  _Float16* vp = VTg + (size_t)(b * 64 + d) * 8192 + n0 + nc;
  *(half8*)vp = v0;
  *(half8*)(vp + 8) = v1;
}

// ---------------------------------------------------------------------------
// attn: flash attention, swapped QK^T (ST = mfma(K,Q)), fused GCN epilogue.
// block: 256 thr = 4 waves, each wave owns 32 q rows (QBLK=128).
// KV-split S in {1,2,4}: grid = S*4*64 blocks (XCD-chunk-swizzled).
// Pipeline (T3/T4): raw s_barrier + counted vmcnt(4), prefetch depth 2 —
// __syncthreads drains vmcnt(0) and serially exposes the prefetch latency
// every tile (round-5 post-mortem: ~2000 cyc/tile critical path, ~85% stall).
// defer-max (T13, THR=8) skips the O-rescale on most tiles.
// ---------------------------------------------------------------------------
#define GL(src, dst)                                                           \
  __builtin_amdgcn_global_load_lds(                                            \
      (const __attribute__((address_space(1))) unsigned*)(src),                \
      (__attribute__((address_space(3))) unsigned*)(dst), 16, 0, 0)

#define STAGE(buf, t)                                                          \
  {                                                                            \
    GL(srcK0 + ((size_t)(t) << 13), &sK[buf][w << 10]);                        \
    GL(srcK0 + ((size_t)(t) << 13) + 1024, &sK[buf][(w << 10) + 512]);         \
    GL(srcV0 + ((size_t)(t) << 7), &sV[buf][w << 10]);                         \
    GL(srcV0 + ((size_t)(t) << 7) + 131072, &sV[buf][(w << 10) + 512]);        \
  }

#define VMCNT4() asm volatile("s_waitcnt vmcnt(4)" ::: "memory")
#define VMCNT0() asm volatile("s_waitcnt vmcnt(0)" ::: "memory")

__global__ __launch_bounds__(256, 4) void attn_kernel(
    const _Float16* __restrict__ Qg, const _Float16* __restrict__ Kg,
    const _Float16* __restrict__ VTg, const float* __restrict__ Gw,
    float* __restrict__ out, _Float16* __restrict__ Zp,
    float* __restrict__ Ma, float* __restrict__ La, int ntiles, int S) {
  __shared__ _Float16 sK[2][4096];
  __shared__ _Float16 sV[2][4096];
  const int tid = threadIdx.x;
  const int w = tid >> 6;   // 0..3
  const int l = tid & 63;
  const int h = l >> 5;
  const int r31 = l & 31;
  // XCD-chunked bid swizzle (T1): blocks sharing one (s,b) K/V stream land on
  // one XCD -> stream is L2-resident. nwg = S*256, always divisible by 8.
  const int nwg = gridDim.x;
  const int hw = blockIdx.x;
  const int bid = (hw & 7) * (nwg >> 3) + (hw >> 3);
  const int qblk = bid & 63;
  const int b = (bid >> 6) & 3;
  const int s = bid >> 8;
  const int t0 = s * ntiles;
  const int qrow = (qblk << 7) + (w << 5) + r31;

  // Q fragments: B-operand layout (col=q=l&31, k = kb*16 + 8h + j)
  half8 qf[4];
  {
    const _Float16* qp = Qg + ((size_t)(b * 8192 + qrow) << 6) + (h << 3);
#pragma unroll
    for (int kb = 0; kb < 4; ++kb) qf[kb] = *(const half8*)(qp + (kb << 4));
  }

  f32x16 o0 = (f32x16)0.f, o1 = (f32x16)0.f;
  float m = -INFINITY, mc = 0.f, lsum = 0.f;

  const int srow = (w << 4) | (l >> 3);  // first staged row (wave covers 16)
  const int sblk = (l & 7) ^ (l >> 3);   // swizzled 16B block in source
  const char* srcK0 =
      (const char*)(Kg + ((size_t)(b * 8192 + t0 * 64 + srow) << 6)) + (sblk << 4);
  const char* srcV0 =
      (const char*)(VTg + ((size_t)(b * 64 + srow) << 13) + t0 * 64) + (sblk << 4);

  // prologue: prefetch tiles 0 and 1 (depth 2), wait only for tile 0.
  STAGE(0, 0);
  STAGE(1, 1);
  VMCNT4();
  __builtin_amdgcn_s_barrier();

#pragma unroll 1
  for (int t = 0; t < ntiles; ++t) {
    const int cur = t & 1;
    const char* pK = (const char*)sK[cur];
    const char* pV = (const char*)sV[cur];

    // ---- ST = K . Q^T : lane has q = l&31, kv = crow(r,h) (+32 for st1)
    f32x16 st0 = (f32x16)0.f, st1 = (f32x16)0.f;
    __builtin_amdgcn_s_setprio(1);
#pragma unroll
    for (int kb = 0; kb < 4; ++kb) {
      const int sl = ((((kb << 1) | h)) ^ (l & 7)) << 4;
      half8 k0 = *(const half8*)(pK + (r31 << 7) + sl);
      half8 k1 = *(const half8*)(pK + ((32 + r31) << 7) + sl);
      st0 = mfma16(k0, qf[kb], st0);
      st1 = mfma16(k1, qf[kb], st1);
    }
    __builtin_amdgcn_s_setprio(0);

    // ---- online softmax; max via max3-friendly tree, defer-max rescale
    float mx[8];
#pragma unroll
    for (int r = 0; r < 8; ++r)
      mx[r] = fmaxf(fmaxf(st0[r], st0[r + 8]), fmaxf(st1[r], st1[r + 8]));
    float pm = fmaxf(fmaxf(fmaxf(fmaxf(mx[0], mx[1]), mx[2]),
                           fmaxf(fmaxf(mx[3], mx[4]), mx[5])),
                     fmaxf(mx[6], mx[7]));
    pm = fmaxf(pm, __shfl_xor(pm, 32));
    if (__any(pm > m + 8.f)) {  // defer-max (T13)
      float mn = fmaxf(m, pm);
      float sc = __builtin_amdgcn_exp2f((m - mn) * LOG2E);
#pragma unroll
      for (int r = 0; r < 16; ++r) { o0[r] *= sc; o1[r] *= sc; }
      lsum *= sc;
      m = mn;
      mc = mn * LOG2E;
    }
#pragma unroll
    for (int r = 0; r < 16; ++r) {
      st0[r] = __builtin_amdgcn_exp2f(fmaf(st0[r], LOG2E, -mc));
      st1[r] = __builtin_amdgcn_exp2f(fmaf(st1[r], LOG2E, -mc));
    }

    // ---- lsum: VALU pairwise + tree
    float sm[16];
#pragma unroll
    for (int r = 0; r < 16; ++r) sm[r] = st0[r] + st1[r];
#pragma unroll
    for (int off = 8; off > 0; off >>= 1) {
#pragma unroll
      for (int r = 0; r < 8; ++r)
        if (r < off) sm[r] += sm[r + off];
    }
    lsum += sm[0] + __shfl_xor(sm[0], 32);

    // ---- P -> f16 B-fragments (cvt_pk + permlane32_swap)
    half8 pf[4];
    pf[0] = pack_frag(st0[0], st0[1], st0[2], st0[3], st0[4], st0[5], st0[6], st0[7]);
    pf[1] = pack_frag(st0[8], st0[9], st0[10], st0[11], st0[12], st0[13], st0[14], st0[15]);
    pf[2] = pack_frag(st1[0], st1[1], st1[2], st1[3], st1[4], st1[5], st1[6], st1[7]);
    pf[3] = pack_frag(st1[8], st1[9], st1[10], st1[11], st1[12], st1[13], st1[14], st1[15]);

    // ---- O^T += V^T . P^T
    __builtin_amdgcn_s_setprio(1);
#pragma unroll
    for (int kb = 0; kb < 4; ++kb) {
      const int sl = ((((kb << 1) | h)) ^ (l & 7)) << 4;
      half8 v0 = *(const half8*)(pV + (r31 << 7) + sl);
      half8 v1 = *(const half8*)(pV + ((32 + r31) << 7) + sl);
      o0 = mfma16(v0, pf[kb], o0);
      o1 = mfma16(v1, pf[kb], o1);
    }
    __builtin_amdgcn_s_setprio(0);

    // ---- pipeline boundary: all waves done reading buf[cur]; refill it
    // with tile t+2; wait t+1's loads (vmcnt(4) -> t+2's 4 stay in flight).
    __builtin_amdgcn_s_barrier();
    if (t + 2 < ntiles) {
      STAGE(cur, t + 2);
      VMCNT4();
    } else {
      VMCNT0();
    }
    __builtin_amdgcn_s_barrier();
  }

  // ---- epilogue: normalize, fused GCN: Z^T = G^T . O^T  (f16 mfma)
  const float inv = 1.f / lsum;
#pragma unroll
  for (int r = 0; r < 16; ++r) { o0[r] *= inv; o1[r] *= inv; }

  half8 ga[2][4];
#pragma unroll
  for (int eb = 0; eb < 2; ++eb) {
#pragma unroll
    for (int kb = 0; kb < 4; ++kb) {
      half8 tt;
#pragma unroll
      for (int j = 0; j < 8; ++j) {
        int dd = (kb << 4) + (h << 3) + j;
        tt[j] = (_Float16)Gw[(dd << 6) + (eb << 5) + r31];
      }
      ga[eb][kb] = tt;
    }
  }
  half8 of[4];
  of[0] = pack_frag(o0[0], o0[1], o0[2], o0[3], o0[4], o0[5], o0[6], o0[7]);
  of[1] = pack_frag(o0[8], o0[9], o0[10], o0[11], o0[12], o0[13], o0[14], o0[15]);
  of[2] = pack_frag(o1[0], o1[1], o1[2], o1[3], o1[4], o1[5], o1[6], o1[7]);
  of[3] = pack_frag(o1[8], o1[9], o1[10], o1[11], o1[12], o1[13], o1[14], o1[15]);
  f32x16 z0 = (f32x16)0.f, z1 = (f32x16)0.f;
#pragma unroll
  for (int kb = 0; kb < 4; ++kb) {
    z0 = mfma16(ga[0][kb], of[kb], z0);
    z1 = mfma16(ga[1][kb], of[kb], z1);
  }
  if (S == 1) {
    float* Orow = out + (size_t)(b * 8192 + qrow) * 64;
#pragma unroll
    for (int r = 0; r < 16; ++r) {
      const int e0 = (r & 3) + ((r >> 2) << 3) + (h << 2);
      Orow[e0] = fmaxf(z0[r], 0.f);
      Orow[e0 + 32] = fmaxf(z1[r], 0.f);
    }
  } else {
    _Float16* Zrow = Zp + ((size_t)((s << 2) + b) * 8192 + qrow) * 64;
#pragma unroll
    for (int r = 0; r < 16; ++r) {
      const int e0 = (r & 3) + ((r >> 2) << 3) + (h << 2);
      Zrow[e0] = (_Float16)z0[r];
      Zrow[e0 + 32] = (_Float16)z1[r];
    }
    if (h == 0) {
      size_t si = (size_t)((s << 2) + b) * 8192 + qrow;
      Ma[si] = m;
      La[si] = lsum;
    }
  }
}

// ---------------------------------------------------------------------------
// merge: combine S splits + relu. grid 2048*256 threads, one 4-elem quad each.
// S is a template param -> a[] fully unrolled, no scratch (rule #20).
// ---------------------------------------------------------------------------
template <int S>
__global__ __launch_bounds__(256) void merge_kernel(
    const _Float16* __restrict__ Zp, const float* __restrict__ Ma,
    const float* __restrict__ La, float* __restrict__ out) {
  const int idx = blockIdx.x * 256 + threadIdx.x;  // quad index
  const int R = idx >> 4;
  const int c4 = (idx & 15) << 2;
  float M = -INFINITY;
#pragma unroll
  for (int s = 0; s < S; ++s) M = fmaxf(M, Ma[R + s * 32768]);
  float a[S];
  float asum = 0.f;
#pragma unroll
  for (int s = 0; s < S; ++s) {
    a[s] = __builtin_amdgcn_exp2f((Ma[R + s * 32768] - M) * LOG2E) *
           La[R + s * 32768];
    asum += a[s];
  }
  const float inv = 1.f / asum;
  float4 acc = make_float4(0.f, 0.f, 0.f, 0.f);
#pragma unroll
  for (int s = 0; s < S; ++s) {
    const half4v z = *(const half4v*)(Zp + ((size_t)(R + s * 32768) * 64 + c4));
    const float as = a[s];
    acc.x = fmaf(as, (float)z[0], acc.x);
    acc.y = fmaf(as, (float)z[1], acc.y);
    acc.z = fmaf(as, (float)z[2], acc.z);
    acc.w = fmaf(as, (float)z[3], acc.w);
  }
  float4 y;
  y.x = fmaxf(acc.x * inv, 0.f);
  y.y = fmaxf(acc.y * inv, 0.f);
  y.z = fmaxf(acc.z * inv, 0.f);
  y.w = fmaxf(acc.w * inv, 0.f);
  *(float4*)(out + (size_t)R * 64 + c4) = y;
}

extern "C" void kernel_launch(void* const* d_in, const int* in_sizes, int n_in,
                              void* d_out, int out_size, void* d_ws, size_t ws_size,
                              hipStream_t stream) {
  const float* x = (const float*)d_in[0];
  const float* W1 = (const float*)d_in[1];
  const float* W2 = (const float*)d_in[2];
  const float* G = (const float*)d_in[3];
  char* ws = (char*)d_ws;
  const size_t MB = (size_t)1 << 20;
  _Float16* Qg = (_Float16*)(ws);
  _Float16* Kg = (_Float16*)(ws + 4 * MB);
  _Float16* VTg = (_Float16*)(ws + 8 * MB);
  float* out = (float*)d_out;

  // KV-split factor gated on workspace size (Zp f16):
  //   S=4 needs 12MB(QKV) + 16MB(Zp) + 1MB(Ma/La) = 29MB
  //   S=2 needs 12 + 8 + 0.5 = 20.5MB
  int S;
  if (ws_size >= 30 * MB) S = 4;
  else if (ws_size >= 21 * MB) S = 2;
  else S = 1;

  _Float16* Zp = (_Float16*)(ws + 12 * MB);
  float* Ma = (float*)(ws + 12 * MB + (size_t)S * 4 * MB);
  float* La = Ma + (size_t)S * 32768;

  prep_kernel<<<dim3(512), dim3(256), 0, stream>>>(x, W1, W2, Qg, Kg, VTg);
  attn_kernel<<<dim3(S * 256), dim3(256), 0, stream>>>(Qg, Kg, VTg, G, out, Zp,
                                                       Ma, La, 128 / S, S);
  if (S == 4)
    merge_kernel<4><<<dim3(2048), dim3(256), 0, stream>>>(Zp, Ma, La, out);
  else if (S == 2)
    merge_kernel<2><<<dim3(2048), dim3(256), 0, stream>>>(Zp, Ma, La, out);
}